// Round 16
// baseline (772.354 us; speedup 1.0000x reference)
//
#include <hip/hip_runtime.h>

#define N_NODES 10000
#define N_EDGES 160000
#define CIN 64
#define COUT 128
#define KTOT 125
#define NBINS (N_NODES * KTOT)          // 1,250,000
#define NPAIRS (N_EDGES * 8)            // 1,280,000
#define EPS 1e-5f

#define CDIV(a,b) (((a)+(b)-1)/(b))

typedef __attribute__((ext_vector_type(8))) short short8;
typedef __attribute__((ext_vector_type(4))) float floatx4;

static __device__ __forceinline__ unsigned short f2b(float f) {
  union { float f; unsigned u; } v; v.f = f;
  unsigned r = v.u + 0x7FFFu + ((v.u >> 16) & 1u);
  return (unsigned short)(r >> 16);
}
static __device__ __forceinline__ float b2f(unsigned short u) {
  union { unsigned u; float f; } v; v.u = ((unsigned)u) << 16;
  return v.f;
}

typedef __attribute__((address_space(1))) const unsigned int guint;
typedef __attribute__((address_space(3))) unsigned int luint;
static __device__ __forceinline__ void ld_g2l16(const void* g, void* l) {
  __builtin_amdgcn_global_load_lds((guint*)g, (luint*)l, 16, 0, 0);
}

// ---------------- edge CSR (dst-sorted edge order) ----------
__global__ void ecount(const int* __restrict__ dst, int* __restrict__ ecnt, int E) {
  int e = blockIdx.x * 256 + threadIdx.x;
  if (e < E) atomicAdd(&ecnt[dst[e]], 1);
}

// single-block exclusive scan over n=10000; seeds ecur; zeroes stats; caps rowptr2
__global__ void escan(const int* __restrict__ cnt, int* __restrict__ rowptr,
                      int* __restrict__ cur, int n, int* __restrict__ rowptr2,
                      float* __restrict__ stats) {
  for (int i = threadIdx.x; i < 6 * 128; i += 256) stats[i] = 0.f;
  __shared__ int buf[256];
  __shared__ int carry;
  if (threadIdx.x == 0) { carry = 0; rowptr[0] = 0; rowptr2[NBINS] = NPAIRS; }
  __syncthreads();
  for (int base = 0; base < n; base += 256) {
    int i = base + threadIdx.x;
    int v = (i < n) ? cnt[i] : 0;
    buf[threadIdx.x] = v;
    __syncthreads();
    for (int s = 1; s < 256; s <<= 1) {
      int t = (threadIdx.x >= s) ? buf[threadIdx.x - s] : 0;
      __syncthreads();
      buf[threadIdx.x] += t;
      __syncthreads();
    }
    if (i < n) {
      int incl = carry + buf[threadIdx.x];
      rowptr[i + 1] = incl;
      cur[i] = incl - v;
    }
    __syncthreads();
    if (threadIdx.x == 255) carry += buf[255];
    __syncthreads();
  }
}

__global__ void efill(const int* __restrict__ dst, int* __restrict__ ecur,
                      int* __restrict__ eorder, int E) {
  int e = blockIdx.x * 256 + threadIdx.x;
  if (e >= E) return;
  int pos = atomicAdd(&ecur[dst[e]], 1);
  eorder[pos] = e;
}

// ---------------- build_pairs: one wave per node ----------------
__global__ __launch_bounds__(256) void build_pairs(
    const int* __restrict__ eorder, const int* __restrict__ erowptr,
    const int* __restrict__ src, const float* __restrict__ attr,
    int* __restrict__ rowptr2, int2* __restrict__ pairs) {
  __shared__ int hist_s[4][126];
  __shared__ int cur_s[4][126];
  int w = threadIdx.x >> 6, lane = threadIdx.x & 63;
  int node = blockIdx.x * 4 + w;
  if (node >= N_NODES) return;
  int* hist = hist_s[w];
  int* cur = cur_s[w];
  hist[lane] = 0;
  if (lane < 61) hist[64 + lane] = 0;
  __builtin_amdgcn_s_waitcnt(0);
  int e0 = erowptr[node], e1 = erowptr[node + 1];
  int deg = e1 - e0;
  float invdeg = 1.0f / fmaxf((float)deg, 1.0f);
  int sub_e = lane >> 3, corner = lane & 7;
  int bit0 = corner & 1, bit1 = (corner >> 1) & 1, bit2 = (corner >> 2) & 1;
  for (int base = 0; base < deg; base += 8) {
    int ei = base + sub_e;
    if (ei < deg) {
      int e = eorder[e0 + ei];
      float v0 = attr[e * 3 + 0] * 4.f;
      float v1 = attr[e * 3 + 1] * 4.f;
      float v2 = attr[e * 3 + 2] * 4.f;
      int i0 = (int)floorf(v0), i1 = (int)floorf(v1), i2 = (int)floorf(v2);
      int k0 = min(max(i0 + bit0, 0), 4);
      int k1 = min(max(i1 + bit1, 0), 4);
      int k2 = min(max(i2 + bit2, 0), 4);
      atomicAdd(&hist[k0 * 25 + k1 * 5 + k2], 1);
    }
  }
  __builtin_amdgcn_s_waitcnt(0);
  int v0 = hist[lane];
  int v1 = (lane < 61) ? hist[64 + lane] : 0;
  int s0 = v0;
#pragma unroll
  for (int d = 1; d < 64; d <<= 1) {
    int t = __shfl_up(s0, d, 64);
    if (lane >= d) s0 += t;
  }
  int excl0 = s0 - v0;
  int tot0 = __shfl(s0, 63, 64);
  int s1 = v1;
#pragma unroll
  for (int d = 1; d < 64; d <<= 1) {
    int t = __shfl_up(s1, d, 64);
    if (lane >= d) s1 += t;
  }
  int excl1 = s1 - v1 + tot0;
  int basep = e0 * 8;
  long rbase = (long)node * KTOT;
  rowptr2[rbase + lane] = basep + excl0;
  cur[lane] = basep + excl0;
  if (lane < 61) {
    rowptr2[rbase + 64 + lane] = basep + excl1;
    cur[64 + lane] = basep + excl1;
  }
  __builtin_amdgcn_s_waitcnt(0);
  for (int base = 0; base < deg; base += 8) {
    int ei = base + sub_e;
    if (ei < deg) {
      int e = eorder[e0 + ei];
      float v0f = attr[e * 3 + 0] * 4.f;
      float v1f = attr[e * 3 + 1] * 4.f;
      float v2f = attr[e * 3 + 2] * 4.f;
      float b0f = floorf(v0f), b1f = floorf(v1f), b2f_ = floorf(v2f);
      float f0 = v0f - b0f, f1 = v1f - b1f, f2 = v2f - b2f_;
      int i0 = (int)b0f, i1 = (int)b1f, i2 = (int)b2f_;
      float wv = (bit0 ? f0 : 1.f - f0) * (bit1 ? f1 : 1.f - f1) * (bit2 ? f2 : 1.f - f2);
      int k0 = min(max(i0 + bit0, 0), 4);
      int k1 = min(max(i1 + bit1, 0), 4);
      int k2 = min(max(i2 + bit2, 0), 4);
      int pos = atomicAdd(&cur[k0 * 25 + k1 * 5 + k2], 1);
      int2 rec; rec.x = src[e]; rec.y = __float_as_int(wv * invdeg);
      pairs[pos] = rec;
    }
  }
}

// ---------------- one-shot convert: xb + all weight transposes ----------------
__global__ void convert_all(const float* __restrict__ x, const float* __restrict__ W1,
                            const float* __restrict__ W2, const float* __restrict__ Wr1,
                            const float* __restrict__ Wrsc, const float* __restrict__ Wr2,
                            const float* __restrict__ Wsc,
                            unsigned short* __restrict__ xb, unsigned short* __restrict__ W1aug,
                            unsigned short* __restrict__ W2t, unsigned short* __restrict__ rootBt,
                            unsigned short* __restrict__ Wr2t) {
  long i = (long)blockIdx.x * 256 + threadIdx.x;
  const long n0 = 640000, n1 = n0 + 1024000, n2 = n1 + 2048000,
             n3 = n2 + 8192, n4 = n3 + 8192, n5 = n4 + 16384, n6 = n5 + 1024000;
  if (i < n0) {
    xb[i] = f2b(x[i]);
  } else if (i < n1) {
    long j = i - n0; int k = (int)(j >> 7), c = (int)(j & 127);
    W1aug[(long)c * 8000 + k] = f2b(W1[j]);
  } else if (i < n2) {
    long j = i - n1; int k = (int)(j >> 7), c = (int)(j & 127);
    W2t[(long)c * 16000 + k] = f2b(W2[j]);
  } else if (i < n3) {
    long j = i - n2; int k = (int)(j >> 7), c = (int)(j & 127);
    rootBt[c * 64 + k] = f2b(Wr1[j]);
  } else if (i < n4) {
    long j = i - n3; int k = (int)(j >> 7), c = (int)(j & 127);
    rootBt[(128 + c) * 64 + k] = f2b(Wrsc[j]);
  } else if (i < n5) {
    long j = i - n4; int k = (int)(j >> 7), c = (int)(j & 127);
    Wr2t[c * 128 + k] = f2b(Wr2[j]);
  } else if (i < n6) {
    long j = i - n5;
    int c = (int)(j / 8000), kk = (int)(j % 8000);
    W1aug[(long)(128 + c) * 8000 + kk] = f2b(Wsc[(kk & 63) * 128 + c]);
  }
}

// ---------------- scatter: 2 bins per wave-instruction ----------------
template<int C>
__global__ __launch_bounds__(256) void scatter_bins(
    const unsigned short* __restrict__ Xb, const int* __restrict__ rowptr2,
    const int2* __restrict__ pairs,
    unsigned short* __restrict__ accb, int bin0, int nbins_chunk) {
  int wb0 = (blockIdx.x * 4 + (threadIdx.x >> 6)) * 8;
  if (wb0 >= nbins_chunk) return;
  int lane = threadIdx.x & 63;
  int bin = bin0 + wb0;
  int bounds = 0;
  if (lane < 9) bounds = rowptr2[bin + lane];
  int b[9];
#pragma unroll
  for (int j = 0; j < 9; j++) b[j] = __shfl(bounds, j, 64);

  int sub = lane >> 5;           // 0: first bin of pair, 1: second
  int half = lane & 31;

#pragma unroll
  for (int j = 0; j < 4; j++) {
    int pA = sub ? b[2 * j + 1] : b[2 * j];
    int pB = sub ? b[2 * j + 2] : b[2 * j + 1];
    int cnt = pB - pA;
    int idx = (cnt > 0) ? pA : 0;
    int2 rec = pairs[idx];
    float w = __int_as_float(rec.y);
    float a0, a1, a2, a3;
    if (C == 64) {
      unsigned u = *(const unsigned*)(Xb + (long)rec.x * 64 + half * 2);
      a0 = (cnt > 0) ? w * b2f((unsigned short)(u & 0xffffu)) : 0.f;
      a1 = (cnt > 0) ? w * b2f((unsigned short)(u >> 16)) : 0.f;
      a2 = a3 = 0.f;
    } else {
      unsigned long long u = *(const unsigned long long*)(Xb + (long)rec.x * 128 + half * 4);
      a0 = (cnt > 0) ? w * b2f((unsigned short)(u & 0xffffu)) : 0.f;
      a1 = (cnt > 0) ? w * b2f((unsigned short)((u >> 16) & 0xffffu)) : 0.f;
      a2 = (cnt > 0) ? w * b2f((unsigned short)((u >> 32) & 0xffffu)) : 0.f;
      a3 = (cnt > 0) ? w * b2f((unsigned short)(u >> 48)) : 0.f;
    }
    for (int p = pA + 1; p < pB; p++) {
      int2 r = pairs[p];
      float w2 = __int_as_float(r.y);
      if (C == 64) {
        unsigned u = *(const unsigned*)(Xb + (long)r.x * 64 + half * 2);
        a0 += w2 * b2f((unsigned short)(u & 0xffffu));
        a1 += w2 * b2f((unsigned short)(u >> 16));
      } else {
        unsigned long long u = *(const unsigned long long*)(Xb + (long)r.x * 128 + half * 4);
        a0 += w2 * b2f((unsigned short)(u & 0xffffu));
        a1 += w2 * b2f((unsigned short)((u >> 16) & 0xffffu));
        a2 += w2 * b2f((unsigned short)((u >> 32) & 0xffffu));
        a3 += w2 * b2f((unsigned short)(u >> 48));
      }
    }
    int wb = wb0 + 2 * j + sub;
    if (wb < nbins_chunk) {
      if (C == 64) {
        unsigned pk = (unsigned)f2b(a0) | ((unsigned)f2b(a1) << 16);
        *(unsigned*)(accb + (long)wb * 64 + half * 2) = pk;
      } else {
        unsigned long long pk = (unsigned long long)((unsigned)f2b(a0) | ((unsigned)f2b(a1) << 16))
                              | ((unsigned long long)((unsigned)f2b(a2) | ((unsigned)f2b(a3) << 16)) << 32);
        *(unsigned long long*)(accb + (long)wb * 128 + half * 4) = pk;
      }
    }
  }
}

// ---------------- LDS-staged MFMA GEMM, 128 cols, K-extension for root GEMM ------
template<int NCOLS, int EC, bool ATOMIC>
__global__ __launch_bounds__(256, 2) void gemm_tile(
    const unsigned short* __restrict__ A, const unsigned short* __restrict__ Aext,
    const unsigned short* __restrict__ Bt, const unsigned short* __restrict__ Bext,
    float* __restrict__ C, int M, int KSP) {
  __shared__ unsigned short As[128 * 32];
  __shared__ unsigned short Bs[128 * 32];
  int wid = threadIdx.x >> 6, lane = threadIdx.x & 63;
  int row0 = blockIdx.x * 128;
  int Ktot = KSP + EC;
  int nslice = gridDim.y;
  int kslice = CDIV(Ktot / 32, nslice) * 32;
  int kbeg = blockIdx.y * kslice;
  int kend = kbeg + kslice; if (kend > Ktot) kend = Ktot;
  if (kbeg >= Ktot) return;

  int sub = lane & 3;
  int rload = lane >> 2;
  int q = lane >> 4, m16 = lane & 15;

  floatx4 acc[2][8];
#pragma unroll
  for (int t = 0; t < 2; t++)
#pragma unroll
    for (int c = 0; c < 8; c++) acc[t][c] = (floatx4){0.f, 0.f, 0.f, 0.f};

  for (int k0 = kbeg; k0 < kend; k0 += 32) {
    __syncthreads();
#pragma unroll
    for (int j = 0; j < 2; j++) {
      int tr = (wid * 2 + j) * 16 + rload;
      int gr = row0 + tr; if (gr >= M) gr = M - 1;
      const unsigned short* ap;
      const unsigned short* bp;
      if (k0 < KSP) {
        ap = A + (long)gr * KSP + k0 + sub * 8;
        bp = Bt + (long)tr * KSP + k0 + sub * 8;
      } else {
        ap = Aext + (long)gr * EC + (k0 - KSP) + sub * 8;
        bp = Bext + (long)tr * EC + (k0 - KSP) + sub * 8;
      }
      ld_g2l16(ap, As + (wid * 2 + j) * 512);
      ld_g2l16(bp, Bs + (wid * 2 + j) * 512);
    }
    __syncthreads();
#pragma unroll
    for (int t = 0; t < 2; t++) {
      int arow = wid * 32 + t * 16 + m16;
      short8 a = *(const short8*)(As + arow * 32 + q * 8);
#pragma unroll
      for (int c = 0; c < 8; c++) {
        short8 b = *(const short8*)(Bs + (c * 16 + m16) * 32 + q * 8);
        acc[t][c] = __builtin_amdgcn_mfma_f32_16x16x32_bf16(a, b, acc[t][c], 0, 0, 0);
      }
    }
  }

#pragma unroll
  for (int t = 0; t < 2; t++) {
#pragma unroll
    for (int c = 0; c < 8; c++) {
#pragma unroll
      for (int r = 0; r < 4; r++) {
        int orow = row0 + wid * 32 + t * 16 + q * 4 + r;
        if (orow < M) {
          float* p = &C[(long)orow * NCOLS + c * 16 + m16];
          if (ATOMIC) atomicAdd(p, acc[t][c][r]);
          else *p = acc[t][c][r];
        }
      }
    }
  }
}

// ---------------- 128x256 tile GEMM with K-extension (conv1+shortcut+roots) ------
template<int EC, bool ATOMIC>
__global__ __launch_bounds__(256, 2) void gemm_tile_w256(
    const unsigned short* __restrict__ A, const unsigned short* __restrict__ Aext,
    const unsigned short* __restrict__ Bt, const unsigned short* __restrict__ Bext,
    float* __restrict__ C, int M, int KSP) {
  __shared__ unsigned short As[128 * 32];
  __shared__ unsigned short Bs[256 * 32];
  int wid = threadIdx.x >> 6, lane = threadIdx.x & 63;
  int row0 = blockIdx.x * 128;
  int Ktot = KSP + EC;
  int nslice = gridDim.y;
  int kslice = CDIV(Ktot / 32, nslice) * 32;
  int kbeg = blockIdx.y * kslice;
  int kend = kbeg + kslice; if (kend > Ktot) kend = Ktot;
  if (kbeg >= Ktot) return;

  int sub = lane & 3;
  int rload = lane >> 2;
  int q = lane >> 4, m16 = lane & 15;

  floatx4 acc[2][16];
#pragma unroll
  for (int t = 0; t < 2; t++)
#pragma unroll
    for (int c = 0; c < 16; c++) acc[t][c] = (floatx4){0.f, 0.f, 0.f, 0.f};

  for (int k0 = kbeg; k0 < kend; k0 += 32) {
    __syncthreads();
    bool sp = (k0 < KSP);
    int ke = sp ? k0 : (k0 - KSP);
#pragma unroll
    for (int j = 0; j < 2; j++) {
      int tr = (wid * 2 + j) * 16 + rload;
      int gr = row0 + tr; if (gr >= M) gr = M - 1;
      const unsigned short* ap = sp ? (A + (long)gr * KSP + ke + sub * 8)
                                    : (Aext + (long)gr * EC + ke + sub * 8);
      ld_g2l16(ap, As + (wid * 2 + j) * 512);
    }
#pragma unroll
    for (int j = 0; j < 4; j++) {
      int tr = (wid * 4 + j) * 16 + rload;
      const unsigned short* bp = sp ? (Bt + (long)tr * KSP + ke + sub * 8)
                                    : (Bext + (long)tr * EC + ke + sub * 8);
      ld_g2l16(bp, Bs + (wid * 4 + j) * 512);
    }
    __syncthreads();
#pragma unroll
    for (int t = 0; t < 2; t++) {
      int arow = wid * 32 + t * 16 + m16;
      short8 a = *(const short8*)(As + arow * 32 + q * 8);
#pragma unroll
      for (int c = 0; c < 16; c++) {
        short8 b = *(const short8*)(Bs + (c * 16 + m16) * 32 + q * 8);
        acc[t][c] = __builtin_amdgcn_mfma_f32_16x16x32_bf16(a, b, acc[t][c], 0, 0, 0);
      }
    }
  }

#pragma unroll
  for (int t = 0; t < 2; t++) {
#pragma unroll
    for (int c = 0; c < 16; c++) {
#pragma unroll
      for (int r = 0; r < 4; r++) {
        int orow = row0 + wid * 32 + t * 16 + q * 4 + r;
        if (orow < M) {
          float* p = &C[(long)orow * 256 + c * 16 + m16];
          if (ATOMIC) atomicAdd(p, acc[t][c][r]);
          else *p = acc[t][c][r];
        }
      }
    }
  }
}

// ---------------- epilogues (root folded into GEMM; weights carry 1/deg) --------
__global__ void finalize_stats(const float* __restrict__ msgaug,
                               const float* __restrict__ bias,
                               float* __restrict__ out, float* __restrict__ stats, int n) {
  int c = threadIdx.x & 127;
  float bv = bias[c];
  float s = 0.f, s2 = 0.f;
  long tot = (long)n * COUT;
  long stride = (long)gridDim.x * 256;
  for (long i = (long)blockIdx.x * 256 + threadIdx.x; i < tot; i += stride) {
    int r = (int)(i >> 7);
    float v = msgaug[(long)r * 256 + c] + bv;
    out[i] = v;
    s += v; s2 += v * v;
  }
  __shared__ float ls[256], ls2[256];
  ls[threadIdx.x] = s; ls2[threadIdx.x] = s2;
  __syncthreads();
  if (threadIdx.x < 128) {
    atomicAdd(&stats[c], ls[threadIdx.x] + ls[threadIdx.x + 128]);
    atomicAdd(&stats[128 + c], ls2[threadIdx.x] + ls2[threadIdx.x + 128]);
  }
}

__global__ void finalize2_dual(const float* __restrict__ msg2, const float* __restrict__ b2,
                               const float* __restrict__ msgaug, const float* __restrict__ bsc,
                               float* __restrict__ h2r, float* __restrict__ sraw,
                               float* __restrict__ stats2, float* __restrict__ statssc, int n) {
  int c = threadIdx.x & 127;
  float bv2 = b2[c], bvsc = bsc[c];
  float sa = 0.f, sb = 0.f, ta = 0.f, tb = 0.f;
  long tot = (long)n * COUT;
  long stride = (long)gridDim.x * 256;
  for (long i = (long)blockIdx.x * 256 + threadIdx.x; i < tot; i += stride) {
    int r = (int)(i >> 7);
    float v2 = msg2[i] + bv2;
    h2r[i] = v2;
    sa += v2; sb += v2 * v2;
    float vs = msgaug[(long)r * 256 + 128 + c] + bvsc;
    sraw[i] = vs;
    ta += vs; tb += vs * vs;
  }
  __shared__ float l0[256], l1[256], l2[256], l3[256];
  l0[threadIdx.x] = sa; l1[threadIdx.x] = sb; l2[threadIdx.x] = ta; l3[threadIdx.x] = tb;
  __syncthreads();
  if (threadIdx.x < 128) {
    atomicAdd(&stats2[c], l0[threadIdx.x] + l0[threadIdx.x + 128]);
    atomicAdd(&stats2[128 + c], l1[threadIdx.x] + l1[threadIdx.x + 128]);
    atomicAdd(&statssc[c], l2[threadIdx.x] + l2[threadIdx.x + 128]);
    atomicAdd(&statssc[128 + c], l3[threadIdx.x] + l3[threadIdx.x + 128]);
  }
}

__global__ void bn_elu_kernel(float* __restrict__ h, unsigned short* __restrict__ hb,
                              const float* __restrict__ stats, const float* __restrict__ g,
                              const float* __restrict__ be, int n) {
  long i = (long)blockIdx.x * 256 + threadIdx.x;
  if (i >= (long)n * COUT) return;
  int c = (int)(i & 127);
  float inv_n = 1.0f / n;
  float mu = stats[c] * inv_n;
  float var = stats[128 + c] * inv_n - mu * mu;
  float v = (h[i] - mu) * rsqrtf(var + EPS) * g[c] + be[c];
  v = v > 0.f ? v : expm1f(v);
  h[i] = v;
  hb[i] = f2b(v);
}

__global__ void final_out_kernel(const float* __restrict__ h2, const float* __restrict__ sraw,
                                 const float* __restrict__ st2, const float* __restrict__ stsc,
                                 const float* __restrict__ g2, const float* __restrict__ be2,
                                 const float* __restrict__ gsc, const float* __restrict__ besc,
                                 float* __restrict__ out, int n) {
  long i = (long)blockIdx.x * 256 + threadIdx.x;
  if (i >= (long)n * COUT) return;
  int c = (int)(i & 127);
  float inv_n = 1.0f / n;
  float mu2 = st2[c] * inv_n;
  float var2 = st2[128 + c] * inv_n - mu2 * mu2;
  float a = (h2[i] - mu2) * rsqrtf(var2 + EPS) * g2[c] + be2[c];
  float musc = stsc[c] * inv_n;
  float varsc = stsc[128 + c] * inv_n - musc * musc;
  float b = (sraw[i] - musc) * rsqrtf(varsc + EPS) * gsc[c] + besc[c];
  float v = a + b;
  out[i] = v > 0.f ? v : expm1f(v);
}

// ---------------- host ----------------
extern "C" void kernel_launch(void* const* d_in, const int* in_sizes, int n_in,
                              void* d_out, int out_size, void* d_ws, size_t ws_size,
                              hipStream_t stream) {
  const float* x    = (const float*)d_in[0];
  const int*   eidx = (const int*)d_in[1];
  const float* attr = (const float*)d_in[2];
  const float* W1   = (const float*)d_in[3];
  const float* Wr1  = (const float*)d_in[4];
  const float* b1   = (const float*)d_in[5];
  const float* g1   = (const float*)d_in[6];
  const float* be1  = (const float*)d_in[7];
  const float* W2   = (const float*)d_in[8];
  const float* Wr2  = (const float*)d_in[9];
  const float* b2   = (const float*)d_in[10];
  const float* g2   = (const float*)d_in[11];
  const float* be2  = (const float*)d_in[12];
  const float* Wsc  = (const float*)d_in[13];
  const float* Wrsc = (const float*)d_in[14];
  const float* bsc  = (const float*)d_in[15];
  const float* gsc  = (const float*)d_in[16];
  const float* besc = (const float*)d_in[17];
  float* out = (float*)d_out;

  const int* src = eidx;
  const int* dst = eidx + N_EDGES;

  char* base = (char*)d_ws;
  size_t off = 0;
  auto alloc = [&](size_t bytes) -> char* {
    char* p = base + off;
    off += (bytes + 255) & ~(size_t)255;
    return p;
  };
  int* ecnt   = (int*)alloc((size_t)N_NODES * 4);
  int* erowptr= (int*)alloc((size_t)(N_NODES + 1) * 4);
  int* ecur   = (int*)alloc((size_t)N_NODES * 4);
  int* eorder = (int*)alloc((size_t)N_EDGES * 4);
  int* rowptr2= (int*)alloc((size_t)(NBINS + 1) * 4);
  int2* pairs = (int2*)alloc((size_t)NPAIRS * 8);
  unsigned short* xb    = (unsigned short*)alloc((size_t)N_NODES * CIN * 2);
  unsigned short* hb    = (unsigned short*)alloc((size_t)N_NODES * COUT * 2);
  unsigned short* W1aug = (unsigned short*)alloc((size_t)256 * KTOT * CIN * 2);
  unsigned short* W2t   = (unsigned short*)alloc((size_t)COUT * KTOT * COUT * 2);
  unsigned short* rootBt= (unsigned short*)alloc((size_t)256 * CIN * 2);
  unsigned short* Wr2t  = (unsigned short*)alloc((size_t)COUT * COUT * 2);
  float* msgaug= (float*)alloc((size_t)N_NODES * 256 * 4);    // conv1+shortcut (zeroed)
  float* msg2  = (float*)alloc((size_t)N_NODES * COUT * 4);   // conv2 (zeroed, adjacent)
  float* h1    = (float*)alloc((size_t)N_NODES * COUT * 4);
  float* h2r   = (float*)alloc((size_t)N_NODES * COUT * 4);
  float* sraw  = (float*)alloc((size_t)N_NODES * COUT * 4);
  float* stats = (float*)alloc(6 * 128 * 4);
  unsigned short* accb = (unsigned short*)(base + off);
  (void)ws_size;
  const int SPLIT1 = 10;  // conv1: 79*10=790 blocks (round-11 measured-good point)
  const int SPLIT2 = 10;  // conv2: 28*10=280 blocks per chunk
  const int CH2 = 3520;   // conv2 chunk: 112.6 MB < 256 MB L3

  hipMemsetAsync(ecnt, 0, (size_t)N_NODES * 4, stream);
  hipMemsetAsync(msgaug, 0, (size_t)N_NODES * (256 + 128) * 4, stream); // msgaug + msg2

  // edge CSR: dst-sorted edge permutation
  ecount<<<CDIV(N_EDGES, 256), 256, 0, stream>>>(dst, ecnt, N_EDGES);
  escan<<<1, 256, 0, stream>>>(ecnt, erowptr, ecur, N_NODES, rowptr2, stats);
  efill<<<CDIV(N_EDGES, 256), 256, 0, stream>>>(dst, ecur, eorder, N_EDGES);

  // per-node pair build (weights carry 1/deg)
  build_pairs<<<CDIV(N_NODES, 4), 256, 0, stream>>>(eorder, erowptr, src, attr,
                                                    rowptr2, pairs);

  const long CONV_TOT = 640000L + 1024000L + 2048000L + 8192 + 8192 + 16384 + 1024000L;
  convert_all<<<CDIV(CONV_TOT, 256), 256, 0, stream>>>(x, W1, W2, Wr1, Wrsc, Wr2, Wsc,
                                                       xb, W1aug, W2t, rootBt, Wr2t);

  // ---- conv1 + shortcut spline + both root GEMMs (K-extension) ----
  {
    scatter_bins<64><<<CDIV(NBINS, 32), 256, 0, stream>>>(xb, rowptr2, pairs, accb,
                                                          0, NBINS);
    dim3 g(CDIV(N_NODES, 128), SPLIT1);
    gemm_tile_w256<64, true><<<g, 256, 0, stream>>>(
        accb, xb, W1aug, rootBt, msgaug, N_NODES, KTOT * CIN);
  }
  finalize_stats<<<64, 256, 0, stream>>>(msgaug, b1, h1, stats, N_NODES);
  bn_elu_kernel<<<CDIV(N_NODES * COUT, 256), 256, 0, stream>>>(h1, hb, stats, g1, be1, N_NODES);

  // ---- conv2 + root GEMM (K-extension), chunked so accb chunk stays L3-resident
  for (int c0 = 0; c0 < N_NODES; c0 += CH2) {
    int cm = (N_NODES - c0 < CH2) ? (N_NODES - c0) : CH2;
    int nbc = cm * KTOT;
    scatter_bins<128><<<CDIV(nbc, 32), 256, 0, stream>>>(hb, rowptr2, pairs, accb,
                                                         c0 * KTOT, nbc);
    dim3 g(CDIV(cm, 128), SPLIT2);
    gemm_tile<COUT, 128, true><<<g, 256, 0, stream>>>(
        accb, hb + (size_t)c0 * COUT, W2t, Wr2t,
        msg2 + (size_t)c0 * COUT, cm, KTOT * COUT);
  }
  finalize2_dual<<<64, 256, 0, stream>>>(msg2, b2, msgaug, bsc, h2r, sraw,
                                         stats + 256, stats + 512, N_NODES);

  // ---- output ----
  final_out_kernel<<<CDIV(N_NODES * COUT, 256), 256, 0, stream>>>(
      h2r, sraw, stats + 256, stats + 512, g2, be2, gsc, besc, out, N_NODES);
}

// Round 17
// 744.448 us; speedup vs baseline: 1.0375x; 1.0375x over previous
//
#include <hip/hip_runtime.h>

#define N_NODES 10000
#define N_EDGES 160000
#define CIN 64
#define COUT 128
#define KTOT 125
#define NBINS (N_NODES * KTOT)          // 1,250,000
#define NPAIRS (N_EDGES * 8)            // 1,280,000
#define EPS 1e-5f

#define CDIV(a,b) (((a)+(b)-1)/(b))

typedef __attribute__((ext_vector_type(8))) short short8;
typedef __attribute__((ext_vector_type(4))) float floatx4;

static __device__ __forceinline__ unsigned short f2b(float f) {
  union { float f; unsigned u; } v; v.f = f;
  unsigned r = v.u + 0x7FFFu + ((v.u >> 16) & 1u);
  return (unsigned short)(r >> 16);
}
static __device__ __forceinline__ float b2f(unsigned short u) {
  union { unsigned u; float f; } v; v.u = ((unsigned)u) << 16;
  return v.f;
}

typedef __attribute__((address_space(1))) const unsigned int guint;
typedef __attribute__((address_space(3))) unsigned int luint;
static __device__ __forceinline__ void ld_g2l16(const void* g, void* l) {
  __builtin_amdgcn_global_load_lds((guint*)g, (luint*)l, 16, 0, 0);
}

// ---------------- edge CSR (dst-sorted edge order) ----------
__global__ void ecount(const int* __restrict__ dst, int* __restrict__ ecnt, int E) {
  int e = blockIdx.x * 256 + threadIdx.x;
  if (e < E) atomicAdd(&ecnt[dst[e]], 1);
}

// single-block exclusive scan over n=10000; seeds ecur; zeroes stats; caps rowptr2
__global__ void escan(const int* __restrict__ cnt, int* __restrict__ rowptr,
                      int* __restrict__ cur, int n, int* __restrict__ rowptr2,
                      float* __restrict__ stats) {
  for (int i = threadIdx.x; i < 6 * 128; i += 256) stats[i] = 0.f;
  __shared__ int buf[256];
  __shared__ int carry;
  if (threadIdx.x == 0) { carry = 0; rowptr[0] = 0; rowptr2[NBINS] = NPAIRS; }
  __syncthreads();
  for (int base = 0; base < n; base += 256) {
    int i = base + threadIdx.x;
    int v = (i < n) ? cnt[i] : 0;
    buf[threadIdx.x] = v;
    __syncthreads();
    for (int s = 1; s < 256; s <<= 1) {
      int t = (threadIdx.x >= s) ? buf[threadIdx.x - s] : 0;
      __syncthreads();
      buf[threadIdx.x] += t;
      __syncthreads();
    }
    if (i < n) {
      int incl = carry + buf[threadIdx.x];
      rowptr[i + 1] = incl;
      cur[i] = incl - v;
    }
    __syncthreads();
    if (threadIdx.x == 255) carry += buf[255];
    __syncthreads();
  }
}

__global__ void efill(const int* __restrict__ dst, int* __restrict__ ecur,
                      int* __restrict__ eorder, int E) {
  int e = blockIdx.x * 256 + threadIdx.x;
  if (e >= E) return;
  int pos = atomicAdd(&ecur[dst[e]], 1);
  eorder[pos] = e;
}

// ---------------- build_pairs: one wave per node ----------------
__global__ __launch_bounds__(256) void build_pairs(
    const int* __restrict__ eorder, const int* __restrict__ erowptr,
    const int* __restrict__ src, const float* __restrict__ attr,
    int* __restrict__ rowptr2, int2* __restrict__ pairs) {
  __shared__ int hist_s[4][126];
  __shared__ int cur_s[4][126];
  int w = threadIdx.x >> 6, lane = threadIdx.x & 63;
  int node = blockIdx.x * 4 + w;
  if (node >= N_NODES) return;
  int* hist = hist_s[w];
  int* cur = cur_s[w];
  hist[lane] = 0;
  if (lane < 61) hist[64 + lane] = 0;
  __builtin_amdgcn_s_waitcnt(0);
  int e0 = erowptr[node], e1 = erowptr[node + 1];
  int deg = e1 - e0;
  float invdeg = 1.0f / fmaxf((float)deg, 1.0f);
  int sub_e = lane >> 3, corner = lane & 7;
  int bit0 = corner & 1, bit1 = (corner >> 1) & 1, bit2 = (corner >> 2) & 1;
  for (int base = 0; base < deg; base += 8) {
    int ei = base + sub_e;
    if (ei < deg) {
      int e = eorder[e0 + ei];
      float v0 = attr[e * 3 + 0] * 4.f;
      float v1 = attr[e * 3 + 1] * 4.f;
      float v2 = attr[e * 3 + 2] * 4.f;
      int i0 = (int)floorf(v0), i1 = (int)floorf(v1), i2 = (int)floorf(v2);
      int k0 = min(max(i0 + bit0, 0), 4);
      int k1 = min(max(i1 + bit1, 0), 4);
      int k2 = min(max(i2 + bit2, 0), 4);
      atomicAdd(&hist[k0 * 25 + k1 * 5 + k2], 1);
    }
  }
  __builtin_amdgcn_s_waitcnt(0);
  int v0 = hist[lane];
  int v1 = (lane < 61) ? hist[64 + lane] : 0;
  int s0 = v0;
#pragma unroll
  for (int d = 1; d < 64; d <<= 1) {
    int t = __shfl_up(s0, d, 64);
    if (lane >= d) s0 += t;
  }
  int excl0 = s0 - v0;
  int tot0 = __shfl(s0, 63, 64);
  int s1 = v1;
#pragma unroll
  for (int d = 1; d < 64; d <<= 1) {
    int t = __shfl_up(s1, d, 64);
    if (lane >= d) s1 += t;
  }
  int excl1 = s1 - v1 + tot0;
  int basep = e0 * 8;
  long rbase = (long)node * KTOT;
  rowptr2[rbase + lane] = basep + excl0;
  cur[lane] = basep + excl0;
  if (lane < 61) {
    rowptr2[rbase + 64 + lane] = basep + excl1;
    cur[64 + lane] = basep + excl1;
  }
  __builtin_amdgcn_s_waitcnt(0);
  for (int base = 0; base < deg; base += 8) {
    int ei = base + sub_e;
    if (ei < deg) {
      int e = eorder[e0 + ei];
      float v0f = attr[e * 3 + 0] * 4.f;
      float v1f = attr[e * 3 + 1] * 4.f;
      float v2f = attr[e * 3 + 2] * 4.f;
      float b0f = floorf(v0f), b1f = floorf(v1f), b2f_ = floorf(v2f);
      float f0 = v0f - b0f, f1 = v1f - b1f, f2 = v2f - b2f_;
      int i0 = (int)b0f, i1 = (int)b1f, i2 = (int)b2f_;
      float wv = (bit0 ? f0 : 1.f - f0) * (bit1 ? f1 : 1.f - f1) * (bit2 ? f2 : 1.f - f2);
      int k0 = min(max(i0 + bit0, 0), 4);
      int k1 = min(max(i1 + bit1, 0), 4);
      int k2 = min(max(i2 + bit2, 0), 4);
      int pos = atomicAdd(&cur[k0 * 25 + k1 * 5 + k2], 1);
      int2 rec; rec.x = src[e]; rec.y = __float_as_int(wv * invdeg);
      pairs[pos] = rec;
    }
  }
}

// ---------------- one-shot convert: xb + all weight transposes ----------------
__global__ void convert_all(const float* __restrict__ x, const float* __restrict__ W1,
                            const float* __restrict__ W2, const float* __restrict__ Wr1,
                            const float* __restrict__ Wrsc, const float* __restrict__ Wr2,
                            const float* __restrict__ Wsc,
                            unsigned short* __restrict__ xb, unsigned short* __restrict__ W1aug,
                            unsigned short* __restrict__ W2t, unsigned short* __restrict__ rootBt,
                            unsigned short* __restrict__ Wr2t) {
  long i = (long)blockIdx.x * 256 + threadIdx.x;
  const long n0 = 640000, n1 = n0 + 1024000, n2 = n1 + 2048000,
             n3 = n2 + 8192, n4 = n3 + 8192, n5 = n4 + 16384, n6 = n5 + 1024000;
  if (i < n0) {
    xb[i] = f2b(x[i]);
  } else if (i < n1) {
    long j = i - n0; int k = (int)(j >> 7), c = (int)(j & 127);
    W1aug[(long)c * 8000 + k] = f2b(W1[j]);
  } else if (i < n2) {
    long j = i - n1; int k = (int)(j >> 7), c = (int)(j & 127);
    W2t[(long)c * 16000 + k] = f2b(W2[j]);
  } else if (i < n3) {
    long j = i - n2; int k = (int)(j >> 7), c = (int)(j & 127);
    rootBt[c * 64 + k] = f2b(Wr1[j]);
  } else if (i < n4) {
    long j = i - n3; int k = (int)(j >> 7), c = (int)(j & 127);
    rootBt[(128 + c) * 64 + k] = f2b(Wrsc[j]);
  } else if (i < n5) {
    long j = i - n4; int k = (int)(j >> 7), c = (int)(j & 127);
    Wr2t[c * 128 + k] = f2b(Wr2[j]);
  } else if (i < n6) {
    long j = i - n5;
    int c = (int)(j / 8000), kk = (int)(j % 8000);
    W1aug[(long)(128 + c) * 8000 + kk] = f2b(Wsc[(kk & 63) * 128 + c]);
  }
}

// ---------------- scatter: 2 bins per wave-instruction ----------------
template<int C>
__global__ __launch_bounds__(256) void scatter_bins(
    const unsigned short* __restrict__ Xb, const int* __restrict__ rowptr2,
    const int2* __restrict__ pairs,
    unsigned short* __restrict__ accb, int bin0, int nbins_chunk) {
  int wb0 = (blockIdx.x * 4 + (threadIdx.x >> 6)) * 8;
  if (wb0 >= nbins_chunk) return;
  int lane = threadIdx.x & 63;
  int bin = bin0 + wb0;
  int bounds = 0;
  if (lane < 9) bounds = rowptr2[bin + lane];
  int b[9];
#pragma unroll
  for (int j = 0; j < 9; j++) b[j] = __shfl(bounds, j, 64);

  int sub = lane >> 5;           // 0: first bin of pair, 1: second
  int half = lane & 31;

#pragma unroll
  for (int j = 0; j < 4; j++) {
    int pA = sub ? b[2 * j + 1] : b[2 * j];
    int pB = sub ? b[2 * j + 2] : b[2 * j + 1];
    int cnt = pB - pA;
    int idx = (cnt > 0) ? pA : 0;
    int2 rec = pairs[idx];
    float w = __int_as_float(rec.y);
    float a0, a1, a2, a3;
    if (C == 64) {
      unsigned u = *(const unsigned*)(Xb + (long)rec.x * 64 + half * 2);
      a0 = (cnt > 0) ? w * b2f((unsigned short)(u & 0xffffu)) : 0.f;
      a1 = (cnt > 0) ? w * b2f((unsigned short)(u >> 16)) : 0.f;
      a2 = a3 = 0.f;
    } else {
      unsigned long long u = *(const unsigned long long*)(Xb + (long)rec.x * 128 + half * 4);
      a0 = (cnt > 0) ? w * b2f((unsigned short)(u & 0xffffu)) : 0.f;
      a1 = (cnt > 0) ? w * b2f((unsigned short)((u >> 16) & 0xffffu)) : 0.f;
      a2 = (cnt > 0) ? w * b2f((unsigned short)((u >> 32) & 0xffffu)) : 0.f;
      a3 = (cnt > 0) ? w * b2f((unsigned short)(u >> 48)) : 0.f;
    }
    for (int p = pA + 1; p < pB; p++) {
      int2 r = pairs[p];
      float w2 = __int_as_float(r.y);
      if (C == 64) {
        unsigned u = *(const unsigned*)(Xb + (long)r.x * 64 + half * 2);
        a0 += w2 * b2f((unsigned short)(u & 0xffffu));
        a1 += w2 * b2f((unsigned short)(u >> 16));
      } else {
        unsigned long long u = *(const unsigned long long*)(Xb + (long)r.x * 128 + half * 4);
        a0 += w2 * b2f((unsigned short)(u & 0xffffu));
        a1 += w2 * b2f((unsigned short)((u >> 16) & 0xffffu));
        a2 += w2 * b2f((unsigned short)((u >> 32) & 0xffffu));
        a3 += w2 * b2f((unsigned short)(u >> 48));
      }
    }
    int wb = wb0 + 2 * j + sub;
    if (wb < nbins_chunk) {
      if (C == 64) {
        unsigned pk = (unsigned)f2b(a0) | ((unsigned)f2b(a1) << 16);
        *(unsigned*)(accb + (long)wb * 64 + half * 2) = pk;
      } else {
        unsigned long long pk = (unsigned long long)((unsigned)f2b(a0) | ((unsigned)f2b(a1) << 16))
                              | ((unsigned long long)((unsigned)f2b(a2) | ((unsigned)f2b(a3) << 16)) << 32);
        *(unsigned long long*)(accb + (long)wb * 128 + half * 4) = pk;
      }
    }
  }
}

// ---------------- LDS-staged MFMA GEMM, 128 cols, K-extension for root GEMM ------
template<int NCOLS, int EC, bool ATOMIC>
__global__ __launch_bounds__(256, 2) void gemm_tile(
    const unsigned short* __restrict__ A, const unsigned short* __restrict__ Aext,
    const unsigned short* __restrict__ Bt, const unsigned short* __restrict__ Bext,
    float* __restrict__ C, int M, int KSP) {
  __shared__ unsigned short As[128 * 32];
  __shared__ unsigned short Bs[128 * 32];
  int wid = threadIdx.x >> 6, lane = threadIdx.x & 63;
  int row0 = blockIdx.x * 128;
  int Ktot = KSP + EC;
  int nslice = gridDim.y;
  int kslice = CDIV(Ktot / 32, nslice) * 32;
  int kbeg = blockIdx.y * kslice;
  int kend = kbeg + kslice; if (kend > Ktot) kend = Ktot;
  if (kbeg >= Ktot) return;

  int sub = lane & 3;
  int rload = lane >> 2;
  int q = lane >> 4, m16 = lane & 15;

  floatx4 acc[2][8];
#pragma unroll
  for (int t = 0; t < 2; t++)
#pragma unroll
    for (int c = 0; c < 8; c++) acc[t][c] = (floatx4){0.f, 0.f, 0.f, 0.f};

  for (int k0 = kbeg; k0 < kend; k0 += 32) {
    __syncthreads();
#pragma unroll
    for (int j = 0; j < 2; j++) {
      int tr = (wid * 2 + j) * 16 + rload;
      int gr = row0 + tr; if (gr >= M) gr = M - 1;
      const unsigned short* ap;
      const unsigned short* bp;
      if (k0 < KSP) {
        ap = A + (long)gr * KSP + k0 + sub * 8;
        bp = Bt + (long)tr * KSP + k0 + sub * 8;
      } else {
        ap = Aext + (long)gr * EC + (k0 - KSP) + sub * 8;
        bp = Bext + (long)tr * EC + (k0 - KSP) + sub * 8;
      }
      ld_g2l16(ap, As + (wid * 2 + j) * 512);
      ld_g2l16(bp, Bs + (wid * 2 + j) * 512);
    }
    __syncthreads();
#pragma unroll
    for (int t = 0; t < 2; t++) {
      int arow = wid * 32 + t * 16 + m16;
      short8 a = *(const short8*)(As + arow * 32 + q * 8);
#pragma unroll
      for (int c = 0; c < 8; c++) {
        short8 b = *(const short8*)(Bs + (c * 16 + m16) * 32 + q * 8);
        acc[t][c] = __builtin_amdgcn_mfma_f32_16x16x32_bf16(a, b, acc[t][c], 0, 0, 0);
      }
    }
  }

#pragma unroll
  for (int t = 0; t < 2; t++) {
#pragma unroll
    for (int c = 0; c < 8; c++) {
#pragma unroll
      for (int r = 0; r < 4; r++) {
        int orow = row0 + wid * 32 + t * 16 + q * 4 + r;
        if (orow < M) {
          float* p = &C[(long)orow * NCOLS + c * 16 + m16];
          if (ATOMIC) atomicAdd(p, acc[t][c][r]);
          else *p = acc[t][c][r];
        }
      }
    }
  }
}

// ---------------- 128x256 tile GEMM with K-extension (conv1+shortcut+roots) ------
template<int EC, bool ATOMIC>
__global__ __launch_bounds__(256, 2) void gemm_tile_w256(
    const unsigned short* __restrict__ A, const unsigned short* __restrict__ Aext,
    const unsigned short* __restrict__ Bt, const unsigned short* __restrict__ Bext,
    float* __restrict__ C, int M, int KSP) {
  __shared__ unsigned short As[128 * 32];
  __shared__ unsigned short Bs[256 * 32];
  int wid = threadIdx.x >> 6, lane = threadIdx.x & 63;
  int row0 = blockIdx.x * 128;
  int Ktot = KSP + EC;
  int nslice = gridDim.y;
  int kslice = CDIV(Ktot / 32, nslice) * 32;
  int kbeg = blockIdx.y * kslice;
  int kend = kbeg + kslice; if (kend > Ktot) kend = Ktot;
  if (kbeg >= Ktot) return;

  int sub = lane & 3;
  int rload = lane >> 2;
  int q = lane >> 4, m16 = lane & 15;

  floatx4 acc[2][16];
#pragma unroll
  for (int t = 0; t < 2; t++)
#pragma unroll
    for (int c = 0; c < 16; c++) acc[t][c] = (floatx4){0.f, 0.f, 0.f, 0.f};

  for (int k0 = kbeg; k0 < kend; k0 += 32) {
    __syncthreads();
    bool sp = (k0 < KSP);
    int ke = sp ? k0 : (k0 - KSP);
#pragma unroll
    for (int j = 0; j < 2; j++) {
      int tr = (wid * 2 + j) * 16 + rload;
      int gr = row0 + tr; if (gr >= M) gr = M - 1;
      const unsigned short* ap = sp ? (A + (long)gr * KSP + ke + sub * 8)
                                    : (Aext + (long)gr * EC + ke + sub * 8);
      ld_g2l16(ap, As + (wid * 2 + j) * 512);
    }
#pragma unroll
    for (int j = 0; j < 4; j++) {
      int tr = (wid * 4 + j) * 16 + rload;
      const unsigned short* bp = sp ? (Bt + (long)tr * KSP + ke + sub * 8)
                                    : (Bext + (long)tr * EC + ke + sub * 8);
      ld_g2l16(bp, Bs + (wid * 4 + j) * 512);
    }
    __syncthreads();
#pragma unroll
    for (int t = 0; t < 2; t++) {
      int arow = wid * 32 + t * 16 + m16;
      short8 a = *(const short8*)(As + arow * 32 + q * 8);
#pragma unroll
      for (int c = 0; c < 16; c++) {
        short8 b = *(const short8*)(Bs + (c * 16 + m16) * 32 + q * 8);
        acc[t][c] = __builtin_amdgcn_mfma_f32_16x16x32_bf16(a, b, acc[t][c], 0, 0, 0);
      }
    }
  }

#pragma unroll
  for (int t = 0; t < 2; t++) {
#pragma unroll
    for (int c = 0; c < 16; c++) {
#pragma unroll
      for (int r = 0; r < 4; r++) {
        int orow = row0 + wid * 32 + t * 16 + q * 4 + r;
        if (orow < M) {
          float* p = &C[(long)orow * 256 + c * 16 + m16];
          if (ATOMIC) atomicAdd(p, acc[t][c][r]);
          else *p = acc[t][c][r];
        }
      }
    }
  }
}

// ---------------- epilogues (root folded into GEMM; weights carry 1/deg) --------
__global__ void finalize_stats(const float* __restrict__ msgaug,
                               const float* __restrict__ bias,
                               float* __restrict__ out, float* __restrict__ stats, int n) {
  int c = threadIdx.x & 127;
  float bv = bias[c];
  float s = 0.f, s2 = 0.f;
  long tot = (long)n * COUT;
  long stride = (long)gridDim.x * 256;
  for (long i = (long)blockIdx.x * 256 + threadIdx.x; i < tot; i += stride) {
    int r = (int)(i >> 7);
    float v = msgaug[(long)r * 256 + c] + bv;
    out[i] = v;
    s += v; s2 += v * v;
  }
  __shared__ float ls[256], ls2[256];
  ls[threadIdx.x] = s; ls2[threadIdx.x] = s2;
  __syncthreads();
  if (threadIdx.x < 128) {
    atomicAdd(&stats[c], ls[threadIdx.x] + ls[threadIdx.x + 128]);
    atomicAdd(&stats[128 + c], ls2[threadIdx.x] + ls2[threadIdx.x + 128]);
  }
}

__global__ void finalize2_dual(const float* __restrict__ msg2, const float* __restrict__ b2,
                               const float* __restrict__ msgaug, const float* __restrict__ bsc,
                               float* __restrict__ h2r, float* __restrict__ sraw,
                               float* __restrict__ stats2, float* __restrict__ statssc, int n) {
  int c = threadIdx.x & 127;
  float bv2 = b2[c], bvsc = bsc[c];
  float sa = 0.f, sb = 0.f, ta = 0.f, tb = 0.f;
  long tot = (long)n * COUT;
  long stride = (long)gridDim.x * 256;
  for (long i = (long)blockIdx.x * 256 + threadIdx.x; i < tot; i += stride) {
    int r = (int)(i >> 7);
    float v2 = msg2[i] + bv2;
    h2r[i] = v2;
    sa += v2; sb += v2 * v2;
    float vs = msgaug[(long)r * 256 + 128 + c] + bvsc;
    sraw[i] = vs;
    ta += vs; tb += vs * vs;
  }
  __shared__ float l0[256], l1[256], l2[256], l3[256];
  l0[threadIdx.x] = sa; l1[threadIdx.x] = sb; l2[threadIdx.x] = ta; l3[threadIdx.x] = tb;
  __syncthreads();
  if (threadIdx.x < 128) {
    atomicAdd(&stats2[c], l0[threadIdx.x] + l0[threadIdx.x + 128]);
    atomicAdd(&stats2[128 + c], l1[threadIdx.x] + l1[threadIdx.x + 128]);
    atomicAdd(&statssc[c], l2[threadIdx.x] + l2[threadIdx.x + 128]);
    atomicAdd(&statssc[128 + c], l3[threadIdx.x] + l3[threadIdx.x + 128]);
  }
}

__global__ void bn_elu_kernel(float* __restrict__ h, unsigned short* __restrict__ hb,
                              const float* __restrict__ stats, const float* __restrict__ g,
                              const float* __restrict__ be, int n) {
  long i = (long)blockIdx.x * 256 + threadIdx.x;
  if (i >= (long)n * COUT) return;
  int c = (int)(i & 127);
  float inv_n = 1.0f / n;
  float mu = stats[c] * inv_n;
  float var = stats[128 + c] * inv_n - mu * mu;
  float v = (h[i] - mu) * rsqrtf(var + EPS) * g[c] + be[c];
  v = v > 0.f ? v : expm1f(v);
  h[i] = v;
  hb[i] = f2b(v);
}

__global__ void final_out_kernel(const float* __restrict__ h2, const float* __restrict__ sraw,
                                 const float* __restrict__ st2, const float* __restrict__ stsc,
                                 const float* __restrict__ g2, const float* __restrict__ be2,
                                 const float* __restrict__ gsc, const float* __restrict__ besc,
                                 float* __restrict__ out, int n) {
  long i = (long)blockIdx.x * 256 + threadIdx.x;
  if (i >= (long)n * COUT) return;
  int c = (int)(i & 127);
  float inv_n = 1.0f / n;
  float mu2 = st2[c] * inv_n;
  float var2 = st2[128 + c] * inv_n - mu2 * mu2;
  float a = (h2[i] - mu2) * rsqrtf(var2 + EPS) * g2[c] + be2[c];
  float musc = stsc[c] * inv_n;
  float varsc = stsc[128 + c] * inv_n - musc * musc;
  float b = (sraw[i] - musc) * rsqrtf(varsc + EPS) * gsc[c] + besc[c];
  float v = a + b;
  out[i] = v > 0.f ? v : expm1f(v);
}

// ---------------- host ----------------
extern "C" void kernel_launch(void* const* d_in, const int* in_sizes, int n_in,
                              void* d_out, int out_size, void* d_ws, size_t ws_size,
                              hipStream_t stream) {
  const float* x    = (const float*)d_in[0];
  const int*   eidx = (const int*)d_in[1];
  const float* attr = (const float*)d_in[2];
  const float* W1   = (const float*)d_in[3];
  const float* Wr1  = (const float*)d_in[4];
  const float* b1   = (const float*)d_in[5];
  const float* g1   = (const float*)d_in[6];
  const float* be1  = (const float*)d_in[7];
  const float* W2   = (const float*)d_in[8];
  const float* Wr2  = (const float*)d_in[9];
  const float* b2   = (const float*)d_in[10];
  const float* g2   = (const float*)d_in[11];
  const float* be2  = (const float*)d_in[12];
  const float* Wsc  = (const float*)d_in[13];
  const float* Wrsc = (const float*)d_in[14];
  const float* bsc  = (const float*)d_in[15];
  const float* gsc  = (const float*)d_in[16];
  const float* besc = (const float*)d_in[17];
  float* out = (float*)d_out;

  const int* src = eidx;
  const int* dst = eidx + N_EDGES;

  char* base = (char*)d_ws;
  size_t off = 0;
  auto alloc = [&](size_t bytes) -> char* {
    char* p = base + off;
    off += (bytes + 255) & ~(size_t)255;
    return p;
  };
  int* ecnt   = (int*)alloc((size_t)N_NODES * 4);
  int* erowptr= (int*)alloc((size_t)(N_NODES + 1) * 4);
  int* ecur   = (int*)alloc((size_t)N_NODES * 4);
  int* eorder = (int*)alloc((size_t)N_EDGES * 4);
  int* rowptr2= (int*)alloc((size_t)(NBINS + 1) * 4);
  int2* pairs = (int2*)alloc((size_t)NPAIRS * 8);
  unsigned short* xb    = (unsigned short*)alloc((size_t)N_NODES * CIN * 2);
  unsigned short* hb    = (unsigned short*)alloc((size_t)N_NODES * COUT * 2);
  unsigned short* W1aug = (unsigned short*)alloc((size_t)256 * KTOT * CIN * 2);
  unsigned short* W2t   = (unsigned short*)alloc((size_t)COUT * KTOT * COUT * 2);
  unsigned short* rootBt= (unsigned short*)alloc((size_t)256 * CIN * 2);
  unsigned short* Wr2t  = (unsigned short*)alloc((size_t)COUT * COUT * 2);
  float* msgaug= (float*)alloc((size_t)N_NODES * 256 * 4);    // conv1+shortcut (zeroed)
  float* msg2  = (float*)alloc((size_t)N_NODES * COUT * 4);   // conv2 (zeroed, adjacent)
  float* h1    = (float*)alloc((size_t)N_NODES * COUT * 4);
  float* h2r   = (float*)alloc((size_t)N_NODES * COUT * 4);
  float* sraw  = (float*)alloc((size_t)N_NODES * COUT * 4);
  float* stats = (float*)alloc(6 * 128 * 4);
  unsigned short* accb = (unsigned short*)(base + off);
  (void)ws_size;
  const int SPLIT1 = 5;   // conv1: 79*5=395 blocks (best-measured saddle point)
  const int SPLIT2 = 10;  // conv2: 28*10=280 blocks per chunk
  const int CH2 = 3520;   // conv2 chunk: 112.6 MB < 256 MB L3

  hipMemsetAsync(ecnt, 0, (size_t)N_NODES * 4, stream);
  hipMemsetAsync(msgaug, 0, (size_t)N_NODES * (256 + 128) * 4, stream); // msgaug + msg2

  // edge CSR: dst-sorted edge permutation
  ecount<<<CDIV(N_EDGES, 256), 256, 0, stream>>>(dst, ecnt, N_EDGES);
  escan<<<1, 256, 0, stream>>>(ecnt, erowptr, ecur, N_NODES, rowptr2, stats);
  efill<<<CDIV(N_EDGES, 256), 256, 0, stream>>>(dst, ecur, eorder, N_EDGES);

  // per-node pair build (weights carry 1/deg)
  build_pairs<<<CDIV(N_NODES, 4), 256, 0, stream>>>(eorder, erowptr, src, attr,
                                                    rowptr2, pairs);

  const long CONV_TOT = 640000L + 1024000L + 2048000L + 8192 + 8192 + 16384 + 1024000L;
  convert_all<<<CDIV(CONV_TOT, 256), 256, 0, stream>>>(x, W1, W2, Wr1, Wrsc, Wr2, Wsc,
                                                       xb, W1aug, W2t, rootBt, Wr2t);

  // ---- conv1 + shortcut spline + both root GEMMs (K-extension) ----
  {
    scatter_bins<64><<<CDIV(NBINS, 32), 256, 0, stream>>>(xb, rowptr2, pairs, accb,
                                                          0, NBINS);
    dim3 g(CDIV(N_NODES, 128), SPLIT1);
    gemm_tile_w256<64, true><<<g, 256, 0, stream>>>(
        accb, xb, W1aug, rootBt, msgaug, N_NODES, KTOT * CIN);
  }
  finalize_stats<<<64, 256, 0, stream>>>(msgaug, b1, h1, stats, N_NODES);
  bn_elu_kernel<<<CDIV(N_NODES * COUT, 256), 256, 0, stream>>>(h1, hb, stats, g1, be1, N_NODES);

  // ---- conv2 + root GEMM (K-extension), chunked so accb chunk stays L3-resident
  for (int c0 = 0; c0 < N_NODES; c0 += CH2) {
    int cm = (N_NODES - c0 < CH2) ? (N_NODES - c0) : CH2;
    int nbc = cm * KTOT;
    scatter_bins<128><<<CDIV(nbc, 32), 256, 0, stream>>>(hb, rowptr2, pairs, accb,
                                                         c0 * KTOT, nbc);
    dim3 g(CDIV(cm, 128), SPLIT2);
    gemm_tile<COUT, 128, true><<<g, 256, 0, stream>>>(
        accb, hb + (size_t)c0 * COUT, W2t, Wr2t,
        msg2 + (size_t)c0 * COUT, cm, KTOT * COUT);
  }
  finalize2_dual<<<64, 256, 0, stream>>>(msg2, b2, msgaug, bsc, h2r, sraw,
                                         stats + 256, stats + 512, N_NODES);

  // ---- output ----
  final_out_kernel<<<CDIV(N_NODES * COUT, 256), 256, 0, stream>>>(
      h2r, sraw, stats + 256, stats + 512, g2, be2, gsc, besc, out, N_NODES);
}